// Round 6
// baseline (184.050 us; speedup 1.0000x reference)
//
#include <hip/hip_runtime.h>
#include <hip/hip_bf16.h>

// MiniEq2Net round 14 — INSTRUMENTATION ROUND 2. B=8, n=256, nin=16, C=32.
//
// r13 measured: strip pass = 10.45 us, kC_base < 18.6 us (stayed under the
// 39.4 us fill rows even when padded). Cycle models are off 6x and no PMC
// row for our kernels has ever been visible. This round pads BOTH kernels
// over the fill threshold:
//   - kC: 3 dummy strip passes  -> kC ~50 us, PMC row visible.
//   - kD: main loop as lambda, 1 real + 1 dummy replay -> Ddur isolates
//     the main-loop share; visible in top-5 if kD main > ~7 us.
// Outputs bit-identical. Dummies: opaque z offset (anti-CSE), asm sinks
// (anti-DCE), scratch-only LDS writes after real reads complete.
// kD/k5 logic otherwise EXACTLY round-12.

#define NB 8
#define NN 256
#define ND 16
#define NC 32
#define W1S 160   // W1 row stride (floats)
#define W2S 160   // W2 row stride (floats)
#define XP 20     // padded x row pitch (floats), 16B-aligned rows
#define KC_NT 64  // kC tiles per b (4 rows each)
#define NDBLK 68  // kD blocks per b (2 pairs each)

using bf16x8 = __attribute__((ext_vector_type(8))) __bf16;
using f32x4  = __attribute__((ext_vector_type(4))) float;

#define MFMA(a, b, c) __builtin_amdgcn_mfma_f32_16x16x32_bf16((a), (b), (c), 0, 0, 0)

// wave-local producer->consumer LDS sync
#define WAVE_LDS_SYNC() do {                      \
    __builtin_amdgcn_wave_barrier();              \
    __builtin_amdgcn_s_waitcnt(0xc07f); /* lgkmcnt(0) */ \
    __builtin_amdgcn_wave_barrier();              \
} while (0)

// Layer-1 A-fragment: av[j'] = xi[q*8+j'] * xj[q*8+j'] for quad<2, else 0.
__device__ __forceinline__ bf16x8 make_av(const float* xi, const float* xj, int quad)
{
    bf16x8 av;
    if (quad < 2) {
        const float4* a = (const float4*)(xi + quad * 8);
        const float4* b = (const float4*)(xj + quad * 8);
        float4 a0 = a[0], a1 = a[1], b0 = b[0], b1 = b[1];
        av[0] = (__bf16)(a0.x * b0.x); av[1] = (__bf16)(a0.y * b0.y);
        av[2] = (__bf16)(a0.z * b0.z); av[3] = (__bf16)(a0.w * b0.w);
        av[4] = (__bf16)(a1.x * b1.x); av[5] = (__bf16)(a1.y * b1.y);
        av[6] = (__bf16)(a1.z * b1.z); av[7] = (__bf16)(a1.w * b1.w);
    } else {
        #pragma unroll
        for (int j = 0; j < 8; ++j) av[j] = (__bf16)0.f;
    }
    return av;
}

__device__ __forceinline__ unsigned pack2(float lo, float hi)
{
    union { __bf16 b[2]; unsigned u; } p;
    p.b[0] = (__bf16)lo; p.b[1] = (__bf16)hi;
    return p.u;
}

// ---------------- kC: 4-row tiles; layer-1 row/diag/total sums + CD2/CR2 ----
// grid (64, NB), 256 threads. Strip loop executed 4x (1 real + 3 dummies).
__global__ __launch_bounds__(256) void kC_rows(
    const float* __restrict__ x, const float* __restrict__ W1,
    const float* __restrict__ b1, const float* __restrict__ W2,
    float* __restrict__ T1g, float* __restrict__ R1, float* __restrict__ Dg1,
    float* __restrict__ TotP, float* __restrict__ CD2, float* __restrict__ CR2,
    __bf16* __restrict__ BQt, __bf16* __restrict__ Wpm,
    float* __restrict__ Wt4)
{
    const int TI = blockIdx.x, b = blockIdx.y, t = threadIdx.x;
    __shared__ __align__(16) float  sX[NN][XP];       // 20 KB
    __shared__ __align__(16) float  sW1[2 * ND][W1S]; // 20 KB
    __shared__ __align__(16) __bf16 sBQ[NC][48];      // 3 KB
    __shared__ float part[16][ND + 1];
    __shared__ float sS[ND];
    __shared__ float sRT[4][NC], sDgL[4][NC], sRow[4][NC], sDiag[4][NC];

    {   // float4 x staging: 1024 float4s, 4 per thread
        const float4* xg4 = (const float4*)(x + b * NN * ND);
        #pragma unroll
        for (int kk = 0; kk < 4; ++kk) {
            int idx = t + kk * 256;              // float4 index
            int row = idx >> 2, c4 = idx & 3;
            *(float4*)&sX[row][c4 * 4] = xg4[idx];
        }
    }
    {   // float4 W1 staging: 1280 float4s, 5 per thread
        const float4* wg1 = (const float4*)W1;
        float4* sw1 = (float4*)&sW1[0][0];
        #pragma unroll
        for (int kk = 0; kk < 5; ++kk) sw1[t + kk * 256] = wg1[t + kk * 256];
    }
    #pragma unroll
    for (int kk = 0; kk < 2; ++kk) {   // A1w B-table (k<16), rest zero
        int idx = t + kk * 256; int c = idx >> 4, k = idx & 15;
        sBQ[c][k] = (__bf16)(W1[(ND + k) * W1S + c * 5 + 0]
                           + W1[(ND + k) * W1S + c * 5 + 1]);
    }
    #pragma unroll
    for (int kk = 0; kk < 4; ++kk) {
        int idx = t + kk * 256;
        sBQ[idx >> 5][16 + (idx & 31)] = (__bf16)0.f;
    }
    __syncthreads();

    {   // column sums S[d]
        int rr = t >> 4, d = t & 15;
        float p = 0.f;
        #pragma unroll
        for (int k = 0; k < 16; ++k) p += sX[rr + (k << 4)][d];
        part[rr][d] = p;
    }
    if (TI == 0 && b == 0) {   // shared tables — once per launch
        if (t < 192) ((float4*)BQt)[t] = ((const float4*)&sBQ[0][0])[t];
        for (int idx = t; idx < 1024; idx += 256) {
            int s = idx >> 5, kp = idx & 31;
            int c = ((kp & 1) << 4) | (kp >> 1);
            float w0 = W2[c * W2S + s * 5 + 0], w1 = W2[c * W2S + s * 5 + 1];
            Wpm[s * 40 + kp]        = (__bf16)((w0 + w1) * 0.5f);
            Wpm[1280 + s * 40 + kp] = (__bf16)((w0 - w1) * 0.5f);
        }
        for (int idx = t; idx < 1024; idx += 256)
            Wt4[(idx >> 5) * 32 + (idx & 31)] = W2[(idx >> 5) * W2S + (idx & 31) * 5 + 4];
    }
    __syncthreads();
    if (t < ND) {
        float s = 0.f;
        #pragma unroll
        for (int k = 0; k < 16; ++k) s += part[k][t];
        sS[t] = s;
    }
    __syncthreads();
    if (t < 128) {   // R1/Dg1/T1 fused for the 4 tile rows (W1 from LDS)
        int i_l = t >> 5, c = t & 31;
        int gi = TI * 4 + i_l;
        float r = 0.f, dg = 0.f, tt = 0.f;
        #pragma unroll
        for (int d = 0; d < ND; ++d) {
            float xi = sX[gi][d], sd = sS[d];
            const float* wa = &sW1[d][c * 5];
            const float* wb = &sW1[ND + d][c * 5];
            r  += xi * wa[3] + xi * sd * wb[3];
            dg += xi * (wa[0] + wa[1] + wa[2]) + xi * xi * wb[2];
            tt += sd * wa[4] + sd * sd * wb[4];
        }
        r *= (1.f / 256.f);
        float t1 = tt * (1.f / 65536.f) + b1[c];
        R1[(b * NN + gi) * NC + c] = r;
        Dg1[(b * NN + gi) * NC + c] = dg;
        sRT[i_l][c] = t1 + r;
        sDgL[i_l][c] = dg;
        if (TI == 0 && i_l == 0) T1g[b * NC + c] = t1;
    }
    __syncthreads();

    const int ln = t & 63, wv = t >> 6;
    const int m = ln & 15, quad = ln >> 4;
    const int gi = TI * 4 + wv;          // this wave's row
    bf16x8 bq0 = *(const bf16x8*)&sBQ[m][8 * quad];
    bf16x8 bq1 = *(const bf16x8*)&sBQ[m + 16][8 * quad];
    float rt0 = sRT[wv][m], rt1 = sRT[wv][m + 16];
    float dg0 = sDgL[wv][m], dg1 = sDgL[wv][m + 16];
    f32x4 zero = {0.f, 0.f, 0.f, 0.f};

    // strip pass: z is an opaque row offset (0 in reality) so dummy passes
    // can't be CSE'd against the real pass while still emitting ds_reads.
    auto strip_pass = [&](int z, float& o0, float& o1, bool wd) {
        float a0 = 0.f, a1 = 0.f;
        for (int jg = 0; jg < 8; ++jg) {
            #pragma unroll
            for (int gg = 0; gg < 2; ++gg) {
                int jrow = jg * 32 + gg * 16 + m;
                bf16x8 av = make_av(&sX[gi + z][0], &sX[jrow + z][0], quad);
                f32x4 q0 = MFMA(av, bq0, zero);
                f32x4 q1 = MFMA(av, bq1, zero);
                int jb = jg * 32 + gg * 16 + quad * 4;
                #pragma unroll
                for (int r = 0; r < 4; ++r) {
                    float v0 = q0[r] + rt0, v1 = q1[r] + rt1;
                    bool dgf = (jb + r == gi);
                    if (dgf) { v0 += dg0; v1 += dg1; }
                    float h0 = fmaxf(v0, 0.f), h1 = fmaxf(v1, 0.f);
                    if (wd && dgf) { sDiag[wv][m] = h0; sDiag[wv][m + 16] = h1; }
                    a0 += h0; a1 += h1;
                }
            }
        }
        o0 = a0; o1 = a1;
    };

    float rs0, rs1;
    strip_pass(0, rs0, rs1, true);        // REAL pass
    #pragma unroll 1
    for (int dp = 0; dp < 3; ++dp) {      // 3 dummy probe passes
        int z = 0; asm volatile("" : "+v"(z));
        float d0, d1; strip_pass(z, d0, d1, false);
        asm volatile("" :: "v"(d0), "v"(d1));
    }

    rs0 += __shfl_down(rs0, 32, 64); rs0 += __shfl_down(rs0, 16, 64);
    rs1 += __shfl_down(rs1, 32, 64); rs1 += __shfl_down(rs1, 16, 64);
    if (ln < 16) { sRow[wv][ln] = rs0; sRow[wv][ln + 16] = rs1; }
    __syncthreads();
    if (t < NC)
        TotP[TI * (NB * NC) + b * NC + t]
            = sRow[0][t] + sRow[1][t] + sRow[2][t] + sRow[3][t];
    if (t < 128) {   // CD2/CR2 for the 4 rows (raw W2, L2-hot)
        int i_l = t >> 5, s = t & 31;
        int gi2 = TI * 4 + i_l;
        float cd = 0.f, cr = 0.f;
        #pragma unroll
        for (int c = 0; c < NC; ++c) {
            cd += sDiag[i_l][c] * W2[c * W2S + s * 5 + 2];
            cr += sRow[i_l][c]  * W2[c * W2S + s * 5 + 3];
        }
        CD2[(b * NN + gi2) * NC + s] = cd;
        CR2[(b * NN + gi2) * NC + s] = cr * (1.f / 256.f);
    }
}

// ---------------- kD: 2 pairs/block, phase-batched layer1+layer2+reduce -----
// grid (68, NB), 256 threads. Main loop run 1 real + 1 dummy (probe).
__global__ __launch_bounds__(256) void kD_main(
    const float* __restrict__ x,
    const __bf16* __restrict__ BQt, const __bf16* __restrict__ Wpm,
    const float* __restrict__ Wt4, const float* __restrict__ b2,
    const float* __restrict__ T1g, const float* __restrict__ R1g,
    const float* __restrict__ Dg1g, const float* __restrict__ CD2g,
    const float* __restrict__ CR2g, const float* __restrict__ TotP,
    float* __restrict__ GP)
{
    const int b = blockIdx.y, t = threadIdx.x;
    // pairs p0 = 2*bx, p1 = 2*bx+1 from the flat TI<=TJ list
    int p0 = 2 * blockIdx.x;
    int TI0 = 0, rem = p0;
    while (rem >= 16 - TI0) { rem -= 16 - TI0; ++TI0; }
    int TJ0 = TI0 + rem;
    // p1 = p0 + 1: next pair in the same row unless row ends
    int TI1 = TI0, TJ1 = TJ0 + 1;
    if (TJ1 >= 16) { TI1 = TI0 + 1; TJ1 = TI1; }
    const bool diag0 = (TI0 == TJ0), diag1 = (TI1 == TJ1);

    __shared__ __align__(16) __bf16 sU[2][4][16][40];  // per-pair, per-wave
    __shared__ __align__(16) __bf16 sV[2][4][16][40];
    __shared__ __align__(16) __bf16 sBQ[NC][48];
    __shared__ __align__(16) __bf16 sWp[NC][40], sWm[NC][40];  // K-permuted
    __shared__ __align__(16) float sXI[2][16][XP], sXJ[2][16][XP];
    __shared__ float sTot[NC], sCT2[NC];
    __shared__ float red[4][NC];

    {   // float4 x staging: 4 tiles x 64 float4, one per thread
        const float4* xg4 = (const float4*)(x + b * NN * ND);
        int tile = t >> 6, idx = t & 63;
        int row = idx >> 2, c4 = idx & 3;
        int gt;
        float* dst;
        if (tile == 0)      { gt = TI0; dst = &sXI[0][row][c4 * 4]; }
        else if (tile == 1) { gt = TI1; dst = &sXI[1][row][c4 * 4]; }
        else if (tile == 2) { gt = TJ0; dst = &sXJ[0][row][c4 * 4]; }
        else                { gt = TJ1; dst = &sXJ[1][row][c4 * 4]; }
        *(float4*)dst = xg4[(gt * 16 + row) * 4 + c4];
    }
    // coalesced table copies
    if (t < 192) ((float4*)&sBQ[0][0])[t] = ((const float4*)BQt)[t];
    {
        const float4* wsrc = (const float4*)Wpm;   // 160 f4 Wp, then 160 f4 Wm
        #pragma unroll
        for (int i = t; i < 320; i += 256) {
            float4 v = wsrc[i];
            if (i < 160) ((float4*)&sWp[0][0])[i] = v;
            else         ((float4*)&sWm[0][0])[i - 160] = v;
        }
    }
    if (t < NC) {   // wave 0: TotP reduce -> sTot
        float tot = 0.f;
        #pragma unroll
        for (int k = 0; k < KC_NT; ++k) tot += TotP[k * (NB * NC) + b * NC + t];
        sTot[t] = tot;
    }
    if (t < 64) {   // wave-local handoff: sTot (wave 0) -> sCT2 (wave 0)
        WAVE_LDS_SYNC();
        if (t < NC) {
            float ct = 0.f;
            #pragma unroll
            for (int c = 0; c < NC; ++c) ct += sTot[c] * Wt4[c * 32 + t];
            sCT2[t] = ct * (1.f / 65536.f) + b2[t];
        }
    }

    const int ln = t & 63, wv = t >> 6;
    const int m = ln & 15, quad = ln >> 4;

    // epilogue constants for both pairs (pre-barrier, L2-hot, static unroll)
    const float* R1b = R1g + b * NN * NC;
    const float* Dgb = Dg1g + b * NN * NC;
    const float* CDb = CD2g + b * NN * NC;
    const float* CRb = CR2g + b * NN * NC;
    float t10 = T1g[b * NC + m], t11 = T1g[b * NC + m + 16];
    float rti[2][4][2], dgi[2][4][2], cri[2][4][2], cdi[2][4][2];
    float rtj[2][4][2], crj[2][4][2];
    #pragma unroll
    for (int k = 0; k < 2; ++k) {
        int TIk = k ? TI1 : TI0, TJk = k ? TJ1 : TJ0;
        #pragma unroll
        for (int gg = 0; gg < 4; ++gg) {
            int rowI = TIk * 16 + wv * 4 + gg;
            rti[k][gg][0] = R1b[rowI * NC + m] + t10;
            rti[k][gg][1] = R1b[rowI * NC + m + 16] + t11;
            dgi[k][gg][0] = Dgb[rowI * NC + m];
            dgi[k][gg][1] = Dgb[rowI * NC + m + 16];
            cri[k][gg][0] = CRb[rowI * NC + m];
            cri[k][gg][1] = CRb[rowI * NC + m + 16];
            cdi[k][gg][0] = CDb[rowI * NC + m];
            cdi[k][gg][1] = CDb[rowI * NC + m + 16];
        }
        #pragma unroll
        for (int r = 0; r < 4; ++r) {
            int rowJ = TJk * 16 + quad * 4 + r;
            rtj[k][r][0] = R1b[rowJ * NC + m] + t10;
            rtj[k][r][1] = R1b[rowJ * NC + m + 16] + t11;
            crj[k][r][0] = CRb[rowJ * NC + m];
            crj[k][r][1] = CRb[rowJ * NC + m + 16];
        }
    }
    __syncthreads();   // single preamble barrier

    float ct0 = sCT2[m], ct1 = sCT2[m + 16];
    #pragma unroll
    for (int k = 0; k < 2; ++k) {
        #pragma unroll
        for (int gg = 0; gg < 4; ++gg) { cri[k][gg][0] += ct0; cri[k][gg][1] += ct1; }
        #pragma unroll
        for (int r = 0; r < 4; ++r) { crj[k][r][0] += ct0; crj[k][r][1] += ct1; }
    }

    bf16x8 bq0 = *(const bf16x8*)&sBQ[m][8 * quad];
    bf16x8 bq1 = *(const bf16x8*)&sBQ[m + 16][8 * quad];
    bf16x8 wp0 = *(const bf16x8*)&sWp[m][8 * quad];
    bf16x8 wp1 = *(const bf16x8*)&sWp[m + 16][8 * quad];
    bf16x8 wm0 = *(const bf16x8*)&sWm[m][8 * quad];
    bf16x8 wm1 = *(const bf16x8*)&sWm[m + 16][8 * quad];
    __bf16* Uw0 = &sU[0][wv][0][0];
    __bf16* Vw0 = &sV[0][wv][0][0];
    __bf16* Uw1 = &sU[1][wv][0][0];
    __bf16* Vw1 = &sV[1][wv][0][0];
    f32x4 zero = {0.f, 0.f, 0.f, 0.f};

    // main pass as lambda; z = opaque row offset for dummy replays
    auto main_pass = [&](int z, float& o0, float& o1) {
        float A0 = 0.f, A1 = 0.f;
        #pragma unroll
        for (int gg = 0; gg < 4; ++gg) {
            int g = wv * 4 + gg;
            __builtin_amdgcn_wave_barrier();   // prior gg's reads before writes
            #pragma unroll
            for (int k = 0; k < 2; ++k) {
                const bool dgb = k ? diag1 : diag0;
                const float* XI = k ? &sXI[1][0][0] : &sXI[0][0][0];
                const float* XJ = k ? &sXJ[1][0][0] : &sXJ[0][0][0];
                __bf16* Uw = k ? Uw1 : Uw0;
                __bf16* Vw = k ? Vw1 : Vw0;
                bf16x8 av = make_av(XI + (g + z) * XP, XJ + (m + z) * XP, quad);
                f32x4 q0 = MFMA(av, bq0, zero);
                f32x4 q1 = MFMA(av, bq1, zero);
                #pragma unroll
                for (int r = 0; r < 4; ++r) {
                    int tj = quad * 4 + r;
                    float a0 = q0[r] + rti[k][gg][0], b0 = q0[r] + rtj[k][r][0];
                    float a1 = q1[r] + rti[k][gg][1], b1 = q1[r] + rtj[k][r][1];
                    if (dgb && tj == g) {
                        a0 += dgi[k][gg][0]; b0 = a0;
                        a1 += dgi[k][gg][1]; b1 = a1;
                    }
                    float hA0 = fmaxf(a0, 0.f), hB0 = fmaxf(b0, 0.f);
                    float hA1 = fmaxf(a1, 0.f), hB1 = fmaxf(b1, 0.f);
                    *(unsigned*)&Uw[tj * 40 + 2 * m] = pack2(hA0 + hB0, hA1 + hB1);
                    *(unsigned*)&Vw[tj * 40 + 2 * m] = pack2(hA0 - hB0, hA1 - hB1);
                }
            }
            WAVE_LDS_SYNC();
            #pragma unroll
            for (int k = 0; k < 2; ++k) {
                const bool dgb = k ? diag1 : diag0;
                const bool mir = !dgb;
                __bf16* Uw = k ? Uw1 : Uw0;
                __bf16* Vw = k ? Vw1 : Vw0;
                bf16x8 ua = *(const bf16x8*)&Uw[m * 40 + 8 * quad];
                bf16x8 va = *(const bf16x8*)&Vw[m * 40 + 8 * quad];
                f32x4 P0 = MFMA(ua, wp0, zero);
                f32x4 M0 = MFMA(va, wm0, zero);
                f32x4 P1 = MFMA(ua, wp1, zero);
                f32x4 M1 = MFMA(va, wm1, zero);
                #pragma unroll
                for (int r = 0; r < 4; ++r) {
                    int tj = quad * 4 + r;
                    float a1v = P0[r] + M0[r] + cri[k][gg][0];
                    float a2v = P0[r] - M0[r] + crj[k][r][0];
                    float e1 = P1[r] + M1[r] + cri[k][gg][1];
                    float e2 = P1[r] - M1[r] + crj[k][r][1];
                    if (dgb && tj == g) { a1v += cdi[k][gg][0]; e1 += cdi[k][gg][1]; }
                    A0 += fmaxf(a1v, 0.f); A1 += fmaxf(e1, 0.f);
                    if (mir) { A0 += fmaxf(a2v, 0.f); A1 += fmaxf(e2, 0.f); }
                }
            }
        }
        o0 = A0; o1 = A1;
    };

    float acc0, acc1;
    main_pass(0, acc0, acc1);             // REAL pass
    {   // dummy probe pass (opaque offset, sunk results; scratch-only LDS)
        int z = 0; asm volatile("" : "+v"(z));
        float d0, d1; main_pass(z, d0, d1);
        asm volatile("" :: "v"(d0), "v"(d1));
    }

    acc0 += __shfl_down(acc0, 32, 64); acc0 += __shfl_down(acc0, 16, 64);
    acc1 += __shfl_down(acc1, 32, 64); acc1 += __shfl_down(acc1, 16, 64);
    if (ln < 16) { red[wv][ln] = acc0; red[wv][ln + 16] = acc1; }
    __syncthreads();
    if (t < NC)
        GP[blockIdx.x * (NB * NC) + b * NC + t]
            = red[0][t] + red[1][t] + red[2][t] + red[3][t];
}

// ---------------- k5: reduce GP (68 partials) + MLP 32->128->128->1 ---------
__global__ __launch_bounds__(256) void k5_mlp(
    const float* __restrict__ GP, const float* __restrict__ D1,
    const float* __restrict__ db1, const float* __restrict__ D2,
    const float* __restrict__ db2, const float* __restrict__ D3,
    const float* __restrict__ db3, float* __restrict__ out)
{
    int b = blockIdx.x, t = threadIdx.x;
    __shared__ float sGp[8][NC], a[NC], h2s[128], r2[2];
    {
        int q = t >> 5, s = t & 31;
        float p = 0.f;
        for (int k = q; k < NDBLK; k += 8) p += GP[k * (NB * NC) + b * NC + s];
        sGp[q][s] = p;
    }
    __syncthreads();
    if (t < NC) {
        float s = 0.f;
        #pragma unroll
        for (int q = 0; q < 8; ++q) s += sGp[q][t];
        a[t] = fmaxf(s, 0.f);
    }
    __syncthreads();
    if (t < 128) {
        float acc = db1[t];
        #pragma unroll
        for (int s = 0; s < NC; ++s) acc += a[s] * D1[s * 128 + t];
        h2s[t] = fmaxf(acc, 0.f);
    }
    __syncthreads();
    if (t < 128) {
        float acc2 = db2[t];
        #pragma unroll 8
        for (int u = 0; u < 128; ++u) acc2 += h2s[u] * D2[u * 128 + t];
        float h3 = fmaxf(acc2, 0.f);
        float v = h3 * D3[t];
        #pragma unroll
        for (int off = 32; off > 0; off >>= 1) v += __shfl_down(v, off, 64);
        if ((t & 63) == 0) r2[t >> 6] = v;
    }
    __syncthreads();
    if (t == 0) out[b] = r2[0] + r2[1] + db3[0];
}

extern "C" void kernel_launch(void* const* d_in, const int* in_sizes, int n_in,
                              void* d_out, int out_size, void* d_ws, size_t ws_size,
                              hipStream_t stream)
{
    const float* x   = (const float*)d_in[0];
    const float* W1  = (const float*)d_in[1];
    const float* b1  = (const float*)d_in[2];
    const float* W2  = (const float*)d_in[3];
    const float* b2  = (const float*)d_in[4];
    const float* D1  = (const float*)d_in[5];
    const float* db1 = (const float*)d_in[6];
    const float* D2  = (const float*)d_in[7];
    const float* db2 = (const float*)d_in[8];
    const float* D3  = (const float*)d_in[9];
    const float* db3 = (const float*)d_in[10];
    float* out = (float*)d_out;

    float* w = (float*)d_ws;
    float* pT1   = w; w += NB * NC;            // 256
    float* pTotP = w; w += KC_NT * NB * NC;    // 16384
    float* pGP   = w; w += NDBLK * NB * NC;    // 17408
    float* pR1   = w; w += NB * NN * NC;       // 65536
    float* pDg1  = w; w += NB * NN * NC;
    float* pCD2  = w; w += NB * NN * NC;
    float* pCR2  = w; w += NB * NN * NC;
    __bf16* pBQt = (__bf16*)w; w += 768;       // 1536 bf16 = 32x48
    __bf16* pWpm = (__bf16*)w; w += 1280;      // 2560 bf16 = Wp[32x40]+Wm[32x40]
    float* pWt4  = w; w += 1024;               // f32 [c][s]

    hipLaunchKernelGGL(kC_rows, dim3(KC_NT, NB), dim3(256), 0, stream,
                       x, W1, b1, W2, pT1, pR1, pDg1, pTotP, pCD2, pCR2,
                       pBQt, pWpm, pWt4);
    hipLaunchKernelGGL(kD_main, dim3(NDBLK, NB), dim3(256), 0, stream,
                       x, pBQt, pWpm, pWt4, b2, pT1, pR1, pDg1, pCD2, pCR2,
                       pTotP, pGP);
    hipLaunchKernelGGL(k5_mlp, dim3(NB), dim3(256), 0, stream,
                       pGP, D1, db1, D2, db2, D3, db3, out);
}

// Round 7
// 110.770 us; speedup vs baseline: 1.6616x; 1.6616x over previous
//
#include <hip/hip_runtime.h>
#include <hip/hip_bf16.h>

// MiniEq2Net round 15. B=8, n=256, nin=16, C=32, DH=128.  Three launches.
//
// r14 instrumentation: kD main loop ~25-30 us of kD ~33; all pipes idle
// (MfmaUtil 1.7%, VALU 17%, HBM 4%) -> latency-serialized LDS round-trips
// at ~1 wave/SIMD. Fix: SWAPPED-OPERAND L1 MFMA (T12 trick).
//   MFMA(bq, av) gives D[row=c][col=j]: lane (m,quad) holds j=m,
//   c=4quad+r. pack2 pairs (c, c+16) -> kp=2c/2c+1 == the sWp
//   K-permutation -> packed U/V ARE L2's A-fragment registers.
// Main loop is now register-only: no sU/sV, no ds_write/ds_read, no
// syncs. Same f32 values -> bit-identical output.
//   - kD: 1 pair/block (grid 136x8), LDS 34.8->~11.5 KB.
//   - epilogue constants re-indexed by channel: float4 loads at
//     R1b[rowI*NC + 4*quad] (+16); rtj by row TJ*16+m; cri/cdi/crj
//     unchanged.
//   - kC: exact round-10/12 form. k5: 136 partials.

#define NB 8
#define NN 256
#define ND 16
#define NC 32
#define W1S 160   // W1 row stride (floats)
#define W2S 160   // W2 row stride (floats)
#define XP 20     // padded x row pitch (floats), 16B-aligned rows
#define KC_NT 64  // kC tiles per b (4 rows each)
#define NDBLK 136 // kD blocks per b (1 pair each)

using bf16x8 = __attribute__((ext_vector_type(8))) __bf16;
using f32x4  = __attribute__((ext_vector_type(4))) float;

#define MFMA(a, b, c) __builtin_amdgcn_mfma_f32_16x16x32_bf16((a), (b), (c), 0, 0, 0)

// wave-local producer->consumer LDS sync (used only in kD preamble)
#define WAVE_LDS_SYNC() do {                      \
    __builtin_amdgcn_wave_barrier();              \
    __builtin_amdgcn_s_waitcnt(0xc07f); /* lgkmcnt(0) */ \
    __builtin_amdgcn_wave_barrier();              \
} while (0)

// Layer-1 fragment: v[j'] = xi[q*8+j'] * xj[q*8+j'] for quad<2, else 0.
// Valid as A-fragment row (old use) or B-fragment col (swapped use).
__device__ __forceinline__ bf16x8 make_av(const float* xi, const float* xj, int quad)
{
    bf16x8 av;
    if (quad < 2) {
        const float4* a = (const float4*)(xi + quad * 8);
        const float4* b = (const float4*)(xj + quad * 8);
        float4 a0 = a[0], a1 = a[1], b0 = b[0], b1 = b[1];
        av[0] = (__bf16)(a0.x * b0.x); av[1] = (__bf16)(a0.y * b0.y);
        av[2] = (__bf16)(a0.z * b0.z); av[3] = (__bf16)(a0.w * b0.w);
        av[4] = (__bf16)(a1.x * b1.x); av[5] = (__bf16)(a1.y * b1.y);
        av[6] = (__bf16)(a1.z * b1.z); av[7] = (__bf16)(a1.w * b1.w);
    } else {
        #pragma unroll
        for (int j = 0; j < 8; ++j) av[j] = (__bf16)0.f;
    }
    return av;
}

__device__ __forceinline__ unsigned pack2(float lo, float hi)
{
    union { __bf16 b[2]; unsigned u; } p;
    p.b[0] = (__bf16)lo; p.b[1] = (__bf16)hi;
    return p.u;
}

// ---------------- kC: 4-row tiles; layer-1 row/diag/total sums + CD2/CR2 ----
// grid (64, NB), 256 threads. Each wave owns row i_l = wv. (round-10 form)
__global__ __launch_bounds__(256) void kC_rows(
    const float* __restrict__ x, const float* __restrict__ W1,
    const float* __restrict__ b1, const float* __restrict__ W2,
    float* __restrict__ T1g, float* __restrict__ R1, float* __restrict__ Dg1,
    float* __restrict__ TotP, float* __restrict__ CD2, float* __restrict__ CR2,
    __bf16* __restrict__ BQt, __bf16* __restrict__ Wpm,
    float* __restrict__ Wt4)
{
    const int TI = blockIdx.x, b = blockIdx.y, t = threadIdx.x;
    __shared__ __align__(16) float  sX[NN][XP];       // 20 KB
    __shared__ __align__(16) float  sW1[2 * ND][W1S]; // 20 KB
    __shared__ __align__(16) __bf16 sBQ[NC][48];      // 3 KB
    __shared__ float part[16][ND + 1];
    __shared__ float sS[ND];
    __shared__ float sRT[4][NC], sDgL[4][NC], sRow[4][NC], sDiag[4][NC];

    {   // float4 x staging: 1024 float4s, 4 per thread
        const float4* xg4 = (const float4*)(x + b * NN * ND);
        #pragma unroll
        for (int kk = 0; kk < 4; ++kk) {
            int idx = t + kk * 256;              // float4 index
            int row = idx >> 2, c4 = idx & 3;
            *(float4*)&sX[row][c4 * 4] = xg4[idx];
        }
    }
    {   // float4 W1 staging: 1280 float4s, 5 per thread
        const float4* wg1 = (const float4*)W1;
        float4* sw1 = (float4*)&sW1[0][0];
        #pragma unroll
        for (int kk = 0; kk < 5; ++kk) sw1[t + kk * 256] = wg1[t + kk * 256];
    }
    #pragma unroll
    for (int kk = 0; kk < 2; ++kk) {   // A1w B-table (k<16), rest zero
        int idx = t + kk * 256; int c = idx >> 4, k = idx & 15;
        sBQ[c][k] = (__bf16)(W1[(ND + k) * W1S + c * 5 + 0]
                           + W1[(ND + k) * W1S + c * 5 + 1]);
    }
    #pragma unroll
    for (int kk = 0; kk < 4; ++kk) {
        int idx = t + kk * 256;
        sBQ[idx >> 5][16 + (idx & 31)] = (__bf16)0.f;
    }
    __syncthreads();

    {   // column sums S[d]
        int rr = t >> 4, d = t & 15;
        float p = 0.f;
        #pragma unroll
        for (int k = 0; k < 16; ++k) p += sX[rr + (k << 4)][d];
        part[rr][d] = p;
    }
    if (TI == 0 && b == 0) {   // shared tables — once per launch
        if (t < 192) ((float4*)BQt)[t] = ((const float4*)&sBQ[0][0])[t];
        for (int idx = t; idx < 1024; idx += 256) {
            int s = idx >> 5, kp = idx & 31;
            int c = ((kp & 1) << 4) | (kp >> 1);
            float w0 = W2[c * W2S + s * 5 + 0], w1 = W2[c * W2S + s * 5 + 1];
            Wpm[s * 40 + kp]        = (__bf16)((w0 + w1) * 0.5f);
            Wpm[1280 + s * 40 + kp] = (__bf16)((w0 - w1) * 0.5f);
        }
        for (int idx = t; idx < 1024; idx += 256)
            Wt4[(idx >> 5) * 32 + (idx & 31)] = W2[(idx >> 5) * W2S + (idx & 31) * 5 + 4];
    }
    __syncthreads();
    if (t < ND) {
        float s = 0.f;
        #pragma unroll
        for (int k = 0; k < 16; ++k) s += part[k][t];
        sS[t] = s;
    }
    __syncthreads();
    if (t < 128) {   // R1/Dg1/T1 fused for the 4 tile rows (W1 from LDS)
        int i_l = t >> 5, c = t & 31;
        int gi = TI * 4 + i_l;
        float r = 0.f, dg = 0.f, tt = 0.f;
        #pragma unroll
        for (int d = 0; d < ND; ++d) {
            float xi = sX[gi][d], sd = sS[d];
            const float* wa = &sW1[d][c * 5];
            const float* wb = &sW1[ND + d][c * 5];
            r  += xi * wa[3] + xi * sd * wb[3];
            dg += xi * (wa[0] + wa[1] + wa[2]) + xi * xi * wb[2];
            tt += sd * wa[4] + sd * sd * wb[4];
        }
        r *= (1.f / 256.f);
        float t1 = tt * (1.f / 65536.f) + b1[c];
        R1[(b * NN + gi) * NC + c] = r;
        Dg1[(b * NN + gi) * NC + c] = dg;
        sRT[i_l][c] = t1 + r;
        sDgL[i_l][c] = dg;
        if (TI == 0 && i_l == 0) T1g[b * NC + c] = t1;
    }
    __syncthreads();

    const int ln = t & 63, wv = t >> 6;
    const int m = ln & 15, quad = ln >> 4;
    const int gi = TI * 4 + wv;          // this wave's row
    bf16x8 bq0 = *(const bf16x8*)&sBQ[m][8 * quad];
    bf16x8 bq1 = *(const bf16x8*)&sBQ[m + 16][8 * quad];
    float rt0 = sRT[wv][m], rt1 = sRT[wv][m + 16];
    float dg0 = sDgL[wv][m], dg1 = sDgL[wv][m + 16];
    f32x4 zero = {0.f, 0.f, 0.f, 0.f};
    float rs0 = 0.f, rs1 = 0.f;

    // barrier-free strip loop: A-fragments in-register from sX
    for (int jg = 0; jg < 8; ++jg) {
        #pragma unroll
        for (int gg = 0; gg < 2; ++gg) {
            int jrow = jg * 32 + gg * 16 + m;
            bf16x8 av = make_av(&sX[gi][0], &sX[jrow][0], quad);
            f32x4 q0 = MFMA(av, bq0, zero);
            f32x4 q1 = MFMA(av, bq1, zero);
            int jb = jg * 32 + gg * 16 + quad * 4;
            #pragma unroll
            for (int r = 0; r < 4; ++r) {
                float v0 = q0[r] + rt0, v1 = q1[r] + rt1;
                bool dgf = (jb + r == gi);
                if (dgf) { v0 += dg0; v1 += dg1; }
                float h0 = fmaxf(v0, 0.f), h1 = fmaxf(v1, 0.f);
                if (dgf) { sDiag[wv][m] = h0; sDiag[wv][m + 16] = h1; }
                rs0 += h0; rs1 += h1;
            }
        }
    }
    rs0 += __shfl_down(rs0, 32, 64); rs0 += __shfl_down(rs0, 16, 64);
    rs1 += __shfl_down(rs1, 32, 64); rs1 += __shfl_down(rs1, 16, 64);
    if (ln < 16) { sRow[wv][ln] = rs0; sRow[wv][ln + 16] = rs1; }
    __syncthreads();
    if (t < NC)
        TotP[TI * (NB * NC) + b * NC + t]
            = sRow[0][t] + sRow[1][t] + sRow[2][t] + sRow[3][t];
    if (t < 128) {   // CD2/CR2 for the 4 rows (raw W2, L2-hot)
        int i_l = t >> 5, s = t & 31;
        int gi2 = TI * 4 + i_l;
        float cd = 0.f, cr = 0.f;
        #pragma unroll
        for (int c = 0; c < NC; ++c) {
            cd += sDiag[i_l][c] * W2[c * W2S + s * 5 + 2];
            cr += sRow[i_l][c]  * W2[c * W2S + s * 5 + 3];
        }
        CD2[(b * NN + gi2) * NC + s] = cd;
        CR2[(b * NN + gi2) * NC + s] = cr * (1.f / 256.f);
    }
}

// ---------------- kD: tile-pair, register-only main loop (swapped MFMA) -----
// grid (136, NB), 256 threads. Single preamble barrier; zero main-loop syncs.
__global__ __launch_bounds__(256) void kD_main(
    const float* __restrict__ x,
    const __bf16* __restrict__ BQt, const __bf16* __restrict__ Wpm,
    const float* __restrict__ Wt4, const float* __restrict__ b2,
    const float* __restrict__ T1g, const float* __restrict__ R1g,
    const float* __restrict__ Dg1g, const float* __restrict__ CD2g,
    const float* __restrict__ CR2g, const float* __restrict__ TotP,
    float* __restrict__ GP)
{
    const int b = blockIdx.y, t = threadIdx.x;
    int TI = 0, rem = blockIdx.x;
    while (rem >= 16 - TI) { rem -= 16 - TI; ++TI; }
    const int TJ = TI + rem;
    const bool diagblk = (TI == TJ), mirror = !diagblk;

    __shared__ __align__(16) __bf16 sBQ[NC][48];
    __shared__ __align__(16) __bf16 sWp[NC][40], sWm[NC][40];  // K-permuted
    __shared__ __align__(16) float sXI[16][XP], sXJ[16][XP];
    __shared__ float sTot[NC], sCT2[NC];
    __shared__ float red[4][NC];

    if (t < 128) {   // float4 x staging: 64 float4s per tile
        const float4* xg4 = (const float4*)(x + b * NN * ND);
        int half = t >> 6, idx = t & 63;      // half 0 -> XI, 1 -> XJ
        int row = idx >> 2, c4 = idx & 3;
        int base = (half ? TJ : TI) * 16;
        float4 v = xg4[(base + row) * 4 + c4];
        float* dst = half ? &sXJ[row][c4 * 4] : &sXI[row][c4 * 4];
        *(float4*)dst = v;
    }
    // coalesced table copies
    if (t < 192) ((float4*)&sBQ[0][0])[t] = ((const float4*)BQt)[t];
    {
        const float4* wsrc = (const float4*)Wpm;   // 160 f4 Wp, then 160 f4 Wm
        #pragma unroll
        for (int i = t; i < 320; i += 256) {
            float4 v = wsrc[i];
            if (i < 160) ((float4*)&sWp[0][0])[i] = v;
            else         ((float4*)&sWm[0][0])[i - 160] = v;
        }
    }
    if (t < NC) {   // wave 0: TotP reduce -> sTot
        float tot = 0.f;
        #pragma unroll
        for (int k = 0; k < KC_NT; ++k) tot += TotP[k * (NB * NC) + b * NC + t];
        sTot[t] = tot;
    }
    if (t < 64) {   // wave-local handoff: sTot (wave 0) -> sCT2 (wave 0)
        WAVE_LDS_SYNC();
        if (t < NC) {
            float ct = 0.f;
            #pragma unroll
            for (int c = 0; c < NC; ++c) ct += sTot[c] * Wt4[c * 32 + t];
            sCT2[t] = ct * (1.f / 65536.f) + b2[t];
        }
    }

    const int ln = t & 63, wv = t >> 6;
    const int m = ln & 15, quad = ln >> 4;

    // ---- epilogue constants (pre-barrier, L2-hot) ----
    // Channel-indexed terms (c = 4*quad + r, and +16): float4 loads.
    const float* R1b = R1g + b * NN * NC;
    const float* Dgb = Dg1g + b * NN * NC;
    const float* CDb = CD2g + b * NN * NC;
    const float* CRb = CR2g + b * NN * NC;

    float4 t1A = *(const float4*)&T1g[b * NC + 4 * quad];
    float4 t1B = *(const float4*)&T1g[b * NC + 16 + 4 * quad];

    float rtiA[4][4], rtiB[4][4], dgiA[4][4], dgiB[4][4];
    float cri[4][2], cdi[4][2];
    #pragma unroll
    for (int gg = 0; gg < 4; ++gg) {
        int rowI = TI * 16 + wv * 4 + gg;
        float4 ra = *(const float4*)&R1b[rowI * NC + 4 * quad];
        float4 rb = *(const float4*)&R1b[rowI * NC + 16 + 4 * quad];
        float4 da = *(const float4*)&Dgb[rowI * NC + 4 * quad];
        float4 db = *(const float4*)&Dgb[rowI * NC + 16 + 4 * quad];
        #pragma unroll
        for (int r = 0; r < 4; ++r) {
            rtiA[gg][r] = ((const float*)&ra)[r] + ((const float*)&t1A)[r];
            rtiB[gg][r] = ((const float*)&rb)[r] + ((const float*)&t1B)[r];
            dgiA[gg][r] = ((const float*)&da)[r];
            dgiB[gg][r] = ((const float*)&db)[r];
        }
        cri[gg][0] = CRb[rowI * NC + m];
        cri[gg][1] = CRb[rowI * NC + m + 16];
        cdi[gg][0] = CDb[rowI * NC + m];
        cdi[gg][1] = CDb[rowI * NC + m + 16];
    }
    // rtj: transposed-cell R1+T1 at row TJ*16+m, channels 4*quad+r (+16)
    float rtjA[4], rtjB[4];
    {
        int rowJ = TJ * 16 + m;
        float4 ra = *(const float4*)&R1b[rowJ * NC + 4 * quad];
        float4 rb = *(const float4*)&R1b[rowJ * NC + 16 + 4 * quad];
        #pragma unroll
        for (int r = 0; r < 4; ++r) {
            rtjA[r] = ((const float*)&ra)[r] + ((const float*)&t1A)[r];
            rtjB[r] = ((const float*)&rb)[r] + ((const float*)&t1B)[r];
        }
    }
    // crj: L2 j-row bcast at row TJ*16+quad*4+r, channel m (+16) — unchanged
    float crj[4][2];
    #pragma unroll
    for (int r = 0; r < 4; ++r) {
        int rowJ = TJ * 16 + quad * 4 + r;
        crj[r][0] = CRb[rowJ * NC + m];
        crj[r][1] = CRb[rowJ * NC + m + 16];
    }
    __syncthreads();   // single preamble barrier

    float ct0 = sCT2[m], ct1 = sCT2[m + 16];
    #pragma unroll
    for (int gg = 0; gg < 4; ++gg) { cri[gg][0] += ct0; cri[gg][1] += ct1; }
    #pragma unroll
    for (int r = 0; r < 4; ++r) { crj[r][0] += ct0; crj[r][1] += ct1; }

    bf16x8 bq0 = *(const bf16x8*)&sBQ[m][8 * quad];
    bf16x8 bq1 = *(const bf16x8*)&sBQ[m + 16][8 * quad];
    bf16x8 wp0 = *(const bf16x8*)&sWp[m][8 * quad];
    bf16x8 wp1 = *(const bf16x8*)&sWp[m + 16][8 * quad];
    bf16x8 wm0 = *(const bf16x8*)&sWm[m][8 * quad];
    bf16x8 wm1 = *(const bf16x8*)&sWm[m + 16][8 * quad];
    f32x4 zero = {0.f, 0.f, 0.f, 0.f};
    float acc0 = 0.f, acc1 = 0.f;

    // register-only main loop: swapped L1 MFMA -> in-register U/V fragments
    #pragma unroll
    for (int gg = 0; gg < 4; ++gg) {
        int g = wv * 4 + gg;
        // L1 swapped: D[row=c][col=j]: lane(m,quad) holds j=m, c=4quad+r
        bf16x8 av = make_av(&sXI[g][0], &sXJ[m][0], quad);
        f32x4 q0 = MFMA(bq0, av, zero);     // channels 0..15
        f32x4 q1 = MFMA(bq1, av, zero);     // channels 16..31
        bf16x8 pa, va;                       // L2 A-fragments (U and V)
        #pragma unroll
        for (int r = 0; r < 4; ++r) {
            float a0 = q0[r] + rtiA[gg][r], b0 = q0[r] + rtjA[r];
            float a1 = q1[r] + rtiB[gg][r], b1 = q1[r] + rtjB[r];
            if (diagblk && m == g) {
                a0 += dgiA[gg][r]; b0 = a0;
                a1 += dgiB[gg][r]; b1 = a1;
            }
            float hA0 = fmaxf(a0, 0.f), hB0 = fmaxf(b0, 0.f);
            float hA1 = fmaxf(a1, 0.f), hB1 = fmaxf(b1, 0.f);
            ((unsigned*)&pa)[r] = pack2(hA0 + hB0, hA1 + hB1);
            ((unsigned*)&va)[r] = pack2(hA0 - hB0, hA1 - hB1);
        }
        // L2: A = packed U/V fragments (row=j=m, k=channels), B = Wp/Wm
        f32x4 P0 = MFMA(pa, wp0, zero);
        f32x4 M0 = MFMA(va, wm0, zero);
        f32x4 P1 = MFMA(pa, wp1, zero);
        f32x4 M1 = MFMA(va, wm1, zero);
        #pragma unroll
        for (int r = 0; r < 4; ++r) {
            int tj = quad * 4 + r;          // j-row of the output
            float a1v = P0[r] + M0[r] + cri[gg][0];
            float a2v = P0[r] - M0[r] + crj[r][0];
            float e1 = P1[r] + M1[r] + cri[gg][1];
            float e2 = P1[r] - M1[r] + crj[r][1];
            if (diagblk && tj == g) { a1v += cdi[gg][0]; e1 += cdi[gg][1]; }
            acc0 += fmaxf(a1v, 0.f); acc1 += fmaxf(e1, 0.f);
            if (mirror) { acc0 += fmaxf(a2v, 0.f); acc1 += fmaxf(e2, 0.f); }
        }
    }

    acc0 += __shfl_down(acc0, 32, 64); acc0 += __shfl_down(acc0, 16, 64);
    acc1 += __shfl_down(acc1, 32, 64); acc1 += __shfl_down(acc1, 16, 64);
    if (ln < 16) { red[wv][ln] = acc0; red[wv][ln + 16] = acc1; }
    __syncthreads();
    if (t < NC)
        GP[blockIdx.x * (NB * NC) + b * NC + t]
            = red[0][t] + red[1][t] + red[2][t] + red[3][t];
}

// ---------------- k5: reduce GP (136 partials) + MLP 32->128->128->1 --------
__global__ __launch_bounds__(256) void k5_mlp(
    const float* __restrict__ GP, const float* __restrict__ D1,
    const float* __restrict__ db1, const float* __restrict__ D2,
    const float* __restrict__ db2, const float* __restrict__ D3,
    const float* __restrict__ db3, float* __restrict__ out)
{
    int b = blockIdx.x, t = threadIdx.x;
    __shared__ float sGp[8][NC], a[NC], h2s[128], r2[2];
    {
        int q = t >> 5, s = t & 31;
        float p = 0.f;
        for (int k = q; k < NDBLK; k += 8) p += GP[k * (NB * NC) + b * NC + s];
        sGp[q][s] = p;
    }
    __syncthreads();
    if (t < NC) {
        float s = 0.f;
        #pragma unroll
        for (int q = 0; q < 8; ++q) s += sGp[q][t];
        a[t] = fmaxf(s, 0.f);
    }
    __syncthreads();
    if (t < 128) {
        float acc = db1[t];
        #pragma unroll
        for (int s = 0; s < NC; ++s) acc += a[s] * D1[s * 128 + t];
        h2s[t] = fmaxf(acc, 0.f);
    }
    __syncthreads();
    if (t < 128) {
        float acc2 = db2[t];
        #pragma unroll 8
        for (int u = 0; u < 128; ++u) acc2 += h2s[u] * D2[u * 128 + t];
        float h3 = fmaxf(acc2, 0.f);
        float v = h3 * D3[t];
        #pragma unroll
        for (int off = 32; off > 0; off >>= 1) v += __shfl_down(v, off, 64);
        if ((t & 63) == 0) r2[t >> 6] = v;
    }
    __syncthreads();
    if (t == 0) out[b] = r2[0] + r2[1] + db3[0];
}

extern "C" void kernel_launch(void* const* d_in, const int* in_sizes, int n_in,
                              void* d_out, int out_size, void* d_ws, size_t ws_size,
                              hipStream_t stream)
{
    const float* x   = (const float*)d_in[0];
    const float* W1  = (const float*)d_in[1];
    const float* b1  = (const float*)d_in[2];
    const float* W2  = (const float*)d_in[3];
    const float* b2  = (const float*)d_in[4];
    const float* D1  = (const float*)d_in[5];
    const float* db1 = (const float*)d_in[6];
    const float* D2  = (const float*)d_in[7];
    const float* db2 = (const float*)d_in[8];
    const float* D3  = (const float*)d_in[9];
    const float* db3 = (const float*)d_in[10];
    float* out = (float*)d_out;

    float* w = (float*)d_ws;
    float* pT1   = w; w += NB * NC;            // 256
    float* pTotP = w; w += KC_NT * NB * NC;    // 16384
    float* pGP   = w; w += NDBLK * NB * NC;    // 34816
    float* pR1   = w; w += NB * NN * NC;       // 65536
    float* pDg1  = w; w += NB * NN * NC;
    float* pCD2  = w; w += NB * NN * NC;
    float* pCR2  = w; w += NB * NN * NC;
    __bf16* pBQt = (__bf16*)w; w += 768;       // 1536 bf16 = 32x48
    __bf16* pWpm = (__bf16*)w; w += 1280;      // 2560 bf16 = Wp[32x40]+Wm[32x40]
    float* pWt4  = w; w += 1024;               // f32 [c][s]

    hipLaunchKernelGGL(kC_rows, dim3(KC_NT, NB), dim3(256), 0, stream,
                       x, W1, b1, W2, pT1, pR1, pDg1, pTotP, pCD2, pCR2,
                       pBQt, pWpm, pWt4);
    hipLaunchKernelGGL(kD_main, dim3(NDBLK, NB), dim3(256), 0, stream,
                       x, pBQt, pWpm, pWt4, b2, pT1, pR1, pDg1, pCD2, pCR2,
                       pTotP, pGP);
    hipLaunchKernelGGL(k5_mlp, dim3(NB), dim3(256), 0, stream,
                       pGP, D1, db1, D2, db2, D3, db3, out);
}